// Round 1
// baseline (1214.580 us; speedup 1.0000x reference)
//
#include <hip/hip_runtime.h>
#include <cstdint>
#include <cstddef>

// ---------------- constants ----------------
#define BATCH   32768
#define BT      4            // samples per workgroup
#define S1      9            // SLOTS+1
#define MEMD    128
#define TOTD    384
#define RROWS   36           // BT*S1
#define NBLK    (BATCH/BT)   // 8192

// d_ws byte offsets (bf16 transposed weights + collapsed MLP)
#define WS_WIN   0            // [128][128] bf16  WinT[n][k]   = W_in[k][n]
#define WS_WQKV  32768        // [384][128] bf16
#define WS_WC    131072       // [128][128] bf16  (W_m1 @ W_m2)^T
#define WS_WGI   163840       // [256][128] bf16
#define WS_WGM   229376       // [256][128] bf16
#define WS_BC    294912       // [128] f32        b_m1 @ W_m2 + b_m2
#define WS_TOTAL 295424

typedef __bf16 bf16x8 __attribute__((ext_vector_type(8)));
typedef float  f32x4  __attribute__((ext_vector_type(4)));

__device__ __forceinline__ float bf2f(unsigned short u){
  union { unsigned int i; float f; } x; x.i = ((unsigned int)u) << 16; return x.f;
}
__device__ __forceinline__ unsigned short f2bf(float f){
  union { float f; unsigned int i; } x; x.f = f;
  unsigned int i = x.i;
  return (unsigned short)((i + 0x7fffu + ((i >> 16) & 1u)) >> 16);  // RNE
}
__device__ __forceinline__ float sigmoidf_(float x){ return 1.f/(1.f+__expf(-x)); }
__device__ __forceinline__ float tanhf_(float x){ float e = __expf(2.f*x); return 1.f - 2.f/(e+1.f); }
__device__ __forceinline__ void unp8(const unsigned short* p, float* f){
  uint4 u = *(const uint4*)p;
  f[0]=bf2f((unsigned short)(u.x&0xffffu)); f[1]=bf2f((unsigned short)(u.x>>16));
  f[2]=bf2f((unsigned short)(u.y&0xffffu)); f[3]=bf2f((unsigned short)(u.y>>16));
  f[4]=bf2f((unsigned short)(u.z&0xffffu)); f[5]=bf2f((unsigned short)(u.z>>16));
  f[6]=bf2f((unsigned short)(u.w&0xffffu)); f[7]=bf2f((unsigned short)(u.w>>16));
}

// ---------------- weight prep: f32 -> bf16 transposed, W_m1@W_m2 collapsed ----------------
__global__ __launch_bounds__(256) void prep_kernel(
    const float* __restrict__ W_in,  const float* __restrict__ W_qkv,
    const float* __restrict__ W_m1,  const float* __restrict__ W_m2,
    const float* __restrict__ b_m1,  const float* __restrict__ b_m2,
    const float* __restrict__ W_gi,  const float* __restrict__ W_gm,
    unsigned short* __restrict__ ws, float* __restrict__ bc)
{
  int gt = blockIdx.x*256 + threadIdx.x;
  int NT = gridDim.x*256;
  for (int i = gt; i < 128*128; i += NT){ int n=i>>7, k=i&127; ws[(WS_WIN >>1)+i] = f2bf(W_in [k*128+n]); }
  for (int i = gt; i < 384*128; i += NT){ int n=i>>7, k=i&127; ws[(WS_WQKV>>1)+i] = f2bf(W_qkv[k*384+n]); }
  for (int i = gt; i < 256*128; i += NT){ int n=i>>7, k=i&127; ws[(WS_WGI >>1)+i] = f2bf(W_gi [k*256+n]); }
  for (int i = gt; i < 256*128; i += NT){ int n=i>>7, k=i&127; ws[(WS_WGM >>1)+i] = f2bf(W_gm [k*256+n]); }
  for (int i = gt; i < 128*128; i += NT){
    int n=i>>7, k=i&127;
    float s = 0.f;
    for (int j=0;j<128;j++) s += W_m1[k*128+j]*W_m2[j*128+n];
    ws[(WS_WC>>1)+i] = f2bf(s);
  }
  for (int i = gt; i < 128; i += NT){
    float s = b_m2[i];
    for (int j=0;j<128;j++) s += b_m1[j]*W_m2[j*128+i];
    bc[i] = s;
  }
}

// ---------------- fused main kernel ----------------
// LDS plan (53248 B total -> 3 blocks/CU):
//  [0,27648)      qkv bf16 [36][384]   ; later: mlp f32 [36][128] ; later: gi f32[4][256]@0 + mem_orig f32[32][128]@4096
//  [27648,39936)  amp bf16 [48][128]   (mp; rows 36..47 zero) ; later mem bf16 ; later tanh(memory) bf16 [32][128]
//  [39936,49152)  sout bf16 [36][128]  (attn out -> mem -> mem2)
//  [49152,53248)  sx bf16 [16][128]    (inputs -> x; rows 4..15 zero)
__global__ __launch_bounds__(256) void rmc_kernel(
    const float* __restrict__ inputs, const float* __restrict__ memory,
    const float* __restrict__ b_in,   const float* __restrict__ b_qkv,
    const float* __restrict__ lnq_g,  const float* __restrict__ lnq_b,
    const float* __restrict__ ln1_g,  const float* __restrict__ ln1_b,
    const float* __restrict__ ln2_g,  const float* __restrict__ ln2_b,
    const float* __restrict__ b_gi,   const float* __restrict__ b_gm,
    const unsigned short* __restrict__ wWin,  const unsigned short* __restrict__ wWqkv,
    const unsigned short* __restrict__ wWc,   const unsigned short* __restrict__ wWgi,
    const unsigned short* __restrict__ wWgm,  const float* __restrict__ bc,
    float* __restrict__ out0, float* __restrict__ out1)
{
  __shared__ __align__(16) unsigned char smem[53248];
  unsigned short* qkv  = (unsigned short*)(smem + 0);
  unsigned short* amp  = (unsigned short*)(smem + 27648);
  unsigned short* sout = (unsigned short*)(smem + 39936);
  unsigned short* sx   = (unsigned short*)(smem + 49152);
  float* mlpb = (float*)(smem + 0);
  float* gib  = (float*)(smem + 0);
  float* memf = (float*)(smem + 4096);
  unsigned short* tanm = amp;

  const int tid  = threadIdx.x;
  const int lane = tid & 63;
  const int wv   = tid >> 6;
  const int l15  = lane & 15;
  const int lg   = lane >> 4;          // k-group 0..3
  const int b0   = blockIdx.x * BT;

  // ---- P0: stage inputs & memory ----
  for (int i = tid; i < 16*128; i += 256){
    int r = i>>7, c = i&127;
    sx[i] = (r < BT) ? f2bf(inputs[(size_t)(b0+r)*128 + c]) : (unsigned short)0;
  }
  for (int i = tid; i < BT*8*128; i += 256){
    int s = i>>10, rem = i&1023, j = rem>>7, c = rem&127;
    amp[(s*S1+j)*128 + c] = f2bf(memory[(size_t)(b0+s)*1024 + j*128 + c]);
  }
  for (int i = tid; i < 12*128; i += 256) amp[RROWS*128 + i] = 0;  // pad rows 36..47
  __syncthreads();

  // ---- P1: x = inputs @ W_in + b_in   (M=16 pad, N=128) ----
  {
    bf16x8 aX[4];
#pragma unroll
    for (int k=0;k<4;k++) aX[k] = *(const bf16x8*)(sx + l15*128 + k*32 + 8*lg);
    f32x4 accX[2];
#pragma unroll
    for (int n=0;n<2;n++){
      int nt = wv*2 + n;
      f32x4 acc = {0.f,0.f,0.f,0.f};
#pragma unroll
      for (int k=0;k<4;k++){
        bf16x8 b = *(const bf16x8*)(wWin + (nt*16 + l15)*128 + k*32 + 8*lg);
        acc = __builtin_amdgcn_mfma_f32_16x16x32_bf16(aX[k], b, acc, 0, 0, 0);
      }
      accX[n] = acc;
    }
    __syncthreads();   // all A-reads of sx done before overwrite
#pragma unroll
    for (int n=0;n<2;n++){
      int nt = wv*2 + n;
#pragma unroll
      for (int r=0;r<4;r++){
        int row = 4*lg + r;
        if (row < BT){
          int col = nt*16 + l15;
          unsigned short h = f2bf(accX[n][r] + b_in[col]);
          sx[row*128 + col] = h;                  // x bf16 (for gi GEMM)
          amp[(row*S1+8)*128 + col] = h;          // mp slot 8
        }
      }
    }
  }
  __syncthreads();

  // ---- P2: qkv_pre = mp @ W_qkv + b_qkv  (M=48 pad, N=384; wave owns 96 cols) ----
  {
    bf16x8 aQ[3][4];
#pragma unroll
    for (int m=0;m<3;m++)
#pragma unroll
      for (int k=0;k<4;k++)
        aQ[m][k] = *(const bf16x8*)(amp + (m*16 + l15)*128 + k*32 + 8*lg);
    f32x4 accQ[3][6];
#pragma unroll
    for (int m=0;m<3;m++)
#pragma unroll
      for (int n=0;n<6;n++) accQ[m][n] = (f32x4){0.f,0.f,0.f,0.f};
#pragma unroll
    for (int n=0;n<6;n++){
      int nt = wv*6 + n;
#pragma unroll
      for (int k=0;k<4;k++){
        bf16x8 b = *(const bf16x8*)(wWqkv + (nt*16 + l15)*128 + k*32 + 8*lg);
#pragma unroll
        for (int m=0;m<3;m++)
          accQ[m][n] = __builtin_amdgcn_mfma_f32_16x16x32_bf16(aQ[m][k], b, accQ[m][n], 0, 0, 0);
      }
    }
#pragma unroll
    for (int m=0;m<3;m++)
#pragma unroll
      for (int n=0;n<6;n++)
#pragma unroll
        for (int r=0;r<4;r++){
          int row = m*16 + 4*lg + r;
          if (row < RROWS){
            int col = (wv*6+n)*16 + l15;
            qkv[row*TOTD + col] = f2bf(accQ[m][n][r] + b_qkv[col]);
          }
        }
  }
  __syncthreads();

  // ---- P3: LN(qkv) in place + fold q-scale 96^-0.5 ----
  {
    const float QSC = 0.1020620726159658f;
    float gq[6], bq[6];
#pragma unroll
    for (int t=0;t<6;t++){ gq[t] = lnq_g[lane+64*t]; bq[t] = lnq_b[lane+64*t]; }
    for (int r = wv; r < RROWS; r += 4){
      float x[6]; float s = 0.f, sq = 0.f;
#pragma unroll
      for (int t=0;t<6;t++){ x[t] = bf2f(qkv[r*TOTD + lane + 64*t]); s += x[t]; sq += x[t]*x[t]; }
#pragma unroll
      for (int o=1;o<64;o<<=1){ s += __shfl_xor(s,o); sq += __shfl_xor(sq,o); }
      float mean = s * (1.f/384.f);
      float var  = sq * (1.f/384.f) - mean*mean;
      float rs   = rsqrtf(var + 1e-5f);
#pragma unroll
      for (int t=0;t<6;t++){
        int c = lane + 64*t;
        float y = gq[t]*(x[t]-mean)*rs + bq[t];
        if ((c % 96) < 32) y *= QSC;
        qkv[r*TOTD + c] = f2bf(y);
      }
    }
  }
  __syncthreads();

  // ---- P4: attention (VALU). task = (s,h,q), 144 tasks ----
  if (tid < BT*4*S1){
    int s = tid/36, h = (tid/9)&3, q = tid%9;
    const unsigned short* base = qkv + (s*S1)*TOTD + h*96;
    float qv[32];
#pragma unroll
    for (int t=0;t<4;t++) unp8(base + q*TOTD + 8*t, qv + 8*t);
    float sc[9]; float mx = -1e30f;
#pragma unroll
    for (int kk=0;kk<9;kk++){
      float kv[32];
#pragma unroll
      for (int t=0;t<4;t++) unp8(base + kk*TOTD + 32 + 8*t, kv + 8*t);
      float a = 0.f;
#pragma unroll
      for (int d=0;d<32;d++) a += qv[d]*kv[d];
      sc[kk] = a; mx = fmaxf(mx, a);
    }
    float sum = 0.f;
#pragma unroll
    for (int kk=0;kk<9;kk++){ sc[kk] = __expf(sc[kk]-mx); sum += sc[kk]; }
    float inv = 1.f/sum;
    float ov[32];
#pragma unroll
    for (int d=0;d<32;d++) ov[d] = 0.f;
#pragma unroll
    for (int kk=0;kk<9;kk++){
      float vv[32];
#pragma unroll
      for (int t=0;t<4;t++) unp8(base + kk*TOTD + 64 + 8*t, vv + 8*t);
      float p = sc[kk];
#pragma unroll
      for (int d=0;d<32;d++) ov[d] += p*vv[d];
    }
#pragma unroll
    for (int d=0;d<32;d++) sout[(s*S1+q)*128 + h*32 + d] = f2bf(ov[d]*inv);
  }
  __syncthreads();

  // ---- P5: mem = LN(mp + out) -> sout (bf16) and amp (bf16, MLP A-operand) ----
  {
    float g0 = ln1_g[lane], g1 = ln1_g[lane+64], e0 = ln1_b[lane], e1 = ln1_b[lane+64];
    for (int r = wv; r < RROWS; r += 4){
      float t0 = bf2f(amp[r*128+lane])    + bf2f(sout[r*128+lane]);
      float t1 = bf2f(amp[r*128+lane+64]) + bf2f(sout[r*128+lane+64]);
      float s = t0+t1, sq = t0*t0 + t1*t1;
#pragma unroll
      for (int o=1;o<64;o<<=1){ s += __shfl_xor(s,o); sq += __shfl_xor(sq,o); }
      float mean = s*(1.f/128.f), var = sq*(1.f/128.f) - mean*mean;
      float rs = rsqrtf(var + 1e-5f);
      float y0 = g0*(t0-mean)*rs + e0;
      float y1 = g1*(t1-mean)*rs + e1;
      unsigned short h0 = f2bf(y0), h1 = f2bf(y1);
      sout[r*128+lane]    = h0; amp[r*128+lane]    = h0;
      sout[r*128+lane+64] = h1; amp[r*128+lane+64] = h1;
    }
  }
  __syncthreads();

  // ---- P6: mlp = mem @ (W_m1 W_m2) + bc   (N=128) ----
  {
    bf16x8 aM[3][4];
#pragma unroll
    for (int m=0;m<3;m++)
#pragma unroll
      for (int k=0;k<4;k++)
        aM[m][k] = *(const bf16x8*)(amp + (m*16 + l15)*128 + k*32 + 8*lg);
    f32x4 accM[3][2];
#pragma unroll
    for (int m=0;m<3;m++)
#pragma unroll
      for (int n=0;n<2;n++) accM[m][n] = (f32x4){0.f,0.f,0.f,0.f};
#pragma unroll
    for (int n=0;n<2;n++){
      int nt = wv*2 + n;
#pragma unroll
      for (int k=0;k<4;k++){
        bf16x8 b = *(const bf16x8*)(wWc + (nt*16 + l15)*128 + k*32 + 8*lg);
#pragma unroll
        for (int m=0;m<3;m++)
          accM[m][n] = __builtin_amdgcn_mfma_f32_16x16x32_bf16(aM[m][k], b, accM[m][n], 0, 0, 0);
      }
    }
    __syncthreads();   // qkv region (aliased by mlpb) free; also all amp reads done
#pragma unroll
    for (int m=0;m<3;m++)
#pragma unroll
      for (int n=0;n<2;n++)
#pragma unroll
        for (int r=0;r<4;r++){
          int row = m*16 + 4*lg + r;
          if (row < RROWS){
            int col = (wv*2+n)*16 + l15;
            mlpb[row*128 + col] = accM[m][n][r] + bc[col];
          }
        }
  }
  __syncthreads();

  // ---- P7: mem2 = LN(mlp + mem) -> sout (skip slot-8 rows) ----
  {
    float g0 = ln2_g[lane], g1 = ln2_g[lane+64], e0 = ln2_b[lane], e1 = ln2_b[lane+64];
    for (int r = wv; r < RROWS; r += 4){
      if ((r % S1) == 8) continue;
      float t0 = mlpb[r*128+lane]    + bf2f(sout[r*128+lane]);
      float t1 = mlpb[r*128+lane+64] + bf2f(sout[r*128+lane+64]);
      float s = t0+t1, sq = t0*t0 + t1*t1;
#pragma unroll
      for (int o=1;o<64;o<<=1){ s += __shfl_xor(s,o); sq += __shfl_xor(sq,o); }
      float mean = s*(1.f/128.f), var = sq*(1.f/128.f) - mean*mean;
      float rs = rsqrtf(var + 1e-5f);
      sout[r*128+lane]    = f2bf(g0*(t0-mean)*rs + e0);
      sout[r*128+lane+64] = f2bf(g1*(t1-mean)*rs + e1);
    }
  }
  __syncthreads();

  // ---- P8: gi = x @ W_gi + b_gi -> gib[4][256]; reload memory + tanh staging ----
  {
    bf16x8 aG[4];
#pragma unroll
    for (int k=0;k<4;k++) aG[k] = *(const bf16x8*)(sx + l15*128 + k*32 + 8*lg);
    f32x4 accG[4];
#pragma unroll
    for (int n=0;n<4;n++) accG[n] = (f32x4){0.f,0.f,0.f,0.f};
#pragma unroll
    for (int n=0;n<4;n++){
      int nt = wv*4 + n;
#pragma unroll
      for (int k=0;k<4;k++){
        bf16x8 b = *(const bf16x8*)(wWgi + (nt*16 + l15)*128 + k*32 + 8*lg);
        accG[n] = __builtin_amdgcn_mfma_f32_16x16x32_bf16(aG[k], b, accG[n], 0, 0, 0);
      }
    }
#pragma unroll
    for (int n=0;n<4;n++)
#pragma unroll
      for (int r=0;r<4;r++){
        int row = 4*lg + r;
        if (row < BT){
          int col = (wv*4+n)*16 + l15;
          gib[row*256 + col] = accG[n][r] + b_gi[col];
        }
      }
    // P8b: memory reload (f32 for forget-path) + tanh(memory) bf16 (gm A-operand)
    for (int i = tid; i < 32*128; i += 256){
      int r = i>>7, c = i&127, s = r>>3, j = r&7;
      float v = memory[(size_t)(b0+s)*1024 + j*128 + c];
      memf[i] = v;
      tanm[i] = f2bf(tanhf_(v));
    }
  }
  __syncthreads();

  // ---- P9: gm = tanh(memory) @ W_gm + b_gm; fused gates -> global ----
  {
    bf16x8 aT[2][4];
#pragma unroll
    for (int m=0;m<2;m++)
#pragma unroll
      for (int k=0;k<4;k++)
        aT[m][k] = *(const bf16x8*)(tanm + (m*16 + l15)*128 + k*32 + 8*lg);
    f32x4 accT[2][4];
#pragma unroll
    for (int m=0;m<2;m++)
#pragma unroll
      for (int t=0;t<4;t++) accT[m][t] = (f32x4){0.f,0.f,0.f,0.f};
    // wave owns gate cols [wv*32, wv*32+32) for both input & forget halves
    const int ntl[4] = {2*wv, 2*wv+1, 8+2*wv, 8+2*wv+1};
#pragma unroll
    for (int t=0;t<4;t++){
#pragma unroll
      for (int k=0;k<4;k++){
        bf16x8 b = *(const bf16x8*)(wWgm + (ntl[t]*16 + l15)*128 + k*32 + 8*lg);
#pragma unroll
        for (int m=0;m<2;m++)
          accT[m][t] = __builtin_amdgcn_mfma_f32_16x16x32_bf16(aT[m][k], b, accT[m][t], 0, 0, 0);
      }
    }
#pragma unroll
    for (int m=0;m<2;m++)
#pragma unroll
      for (int p=0;p<2;p++)
#pragma unroll
        for (int r=0;r<4;r++){
          int row = m*16 + 4*lg + r;       // 0..31
          int s = row>>3, j = row&7;
          int c = wv*32 + p*16 + l15;      // 0..127
          float g_i = accT[m][p][r]   + b_gm[c]     + gib[s*256 + c];
          float g_f = accT[m][2+p][r] + b_gm[128+c] + gib[s*256 + 128 + c] + 1.0f;
          float ig = sigmoidf_(g_i), fg = sigmoidf_(g_f);
          float m2 = bf2f(sout[(s*S1+j)*128 + c]);
          float nm = ig*tanhf_(m2) + fg*memf[row*128 + c];
          size_t o = (size_t)(b0+s)*1024 + (size_t)(j*128 + c);
          out0[o] = nm;
          out1[o] = nm;
        }
  }
}

// ---------------- launch ----------------
extern "C" void kernel_launch(void* const* d_in, const int* in_sizes, int n_in,
                              void* d_out, int out_size, void* d_ws, size_t ws_size,
                              hipStream_t stream) {
  const float* inputs = (const float*)d_in[0];
  const float* memory = (const float*)d_in[1];
  const float* W_in   = (const float*)d_in[2];
  const float* b_in   = (const float*)d_in[3];
  const float* W_qkv  = (const float*)d_in[4];
  const float* b_qkv  = (const float*)d_in[5];
  const float* lnq_g  = (const float*)d_in[6];
  const float* lnq_b  = (const float*)d_in[7];
  const float* ln1_g  = (const float*)d_in[8];
  const float* ln1_b  = (const float*)d_in[9];
  const float* W_m1   = (const float*)d_in[10];
  const float* b_m1   = (const float*)d_in[11];
  const float* W_m2   = (const float*)d_in[12];
  const float* b_m2   = (const float*)d_in[13];
  const float* ln2_g  = (const float*)d_in[14];
  const float* ln2_b  = (const float*)d_in[15];
  const float* W_gi   = (const float*)d_in[16];
  const float* b_gi   = (const float*)d_in[17];
  const float* W_gm   = (const float*)d_in[18];
  const float* b_gm   = (const float*)d_in[19];

  unsigned short* ws16 = (unsigned short*)d_ws;
  float* bc = (float*)((char*)d_ws + WS_BC);
  const unsigned short* wWin  = (const unsigned short*)((char*)d_ws + WS_WIN);
  const unsigned short* wWqkv = (const unsigned short*)((char*)d_ws + WS_WQKV);
  const unsigned short* wWc   = (const unsigned short*)((char*)d_ws + WS_WC);
  const unsigned short* wWgi  = (const unsigned short*)((char*)d_ws + WS_WGI);
  const unsigned short* wWgm  = (const unsigned short*)((char*)d_ws + WS_WGM);

  float* out0 = (float*)d_out;
  float* out1 = out0 + (size_t)BATCH*1024;

  prep_kernel<<<dim3(256), dim3(256), 0, stream>>>(
      W_in, W_qkv, W_m1, W_m2, b_m1, b_m2, W_gi, W_gm, ws16, bc);

  rmc_kernel<<<dim3(NBLK), dim3(256), 0, stream>>>(
      inputs, memory, b_in, b_qkv, lnq_g, lnq_b, ln1_g, ln1_b, ln2_g, ln2_b,
      b_gi, b_gm, wWin, wWqkv, wWc, wWgi, wWgm, bc, out0, out1);
}

// Round 2
// 1025.895 us; speedup vs baseline: 1.1839x; 1.1839x over previous
//
#include <hip/hip_runtime.h>
#include <cstdint>
#include <cstddef>

// ---------------- constants ----------------
#define BATCH   32768
#define BT      4            // samples per workgroup
#define S1      9            // SLOTS+1
#define RROWS   36           // BT*S1
#define NBLK    (BATCH/BT)   // 8192

// d_ws byte offsets (bf16 transposed weights + collapsed MLP)
#define WS_WIN   0            // [128][128] bf16  WinT[n][k] = W_in[k][n]
#define WS_WQKV  32768        // [384][128] bf16
#define WS_WC    131072       // [128][128] bf16  (W_m1 @ W_m2)^T
#define WS_WGI   163840       // [256][128] bf16
#define WS_WGM   229376       // [256][128] bf16
#define WS_BC    294912       // [128] f32        b_m1 @ W_m2 + b_m2

typedef __bf16 bf16x8 __attribute__((ext_vector_type(8)));
typedef float  f32x4  __attribute__((ext_vector_type(4)));

__device__ __forceinline__ float sigmoidf_(float x){ return 1.f/(1.f+__expf(-x)); }
__device__ __forceinline__ float tanhf_(float x){ float e = __expf(2.f*x); return 1.f - 2.f/(e+1.f); }

// XOR bank swizzle: permute 16B blocks within each row by row&7 (T2 recipe).
// All accesses of size <=16B remain inside one 16B block (XOR touches bits 4..6),
// so b128/b64/b32/b16 reads+writes all work if EVERY access uses this helper.
__device__ __forceinline__ char* swz(char* base, int row, int stride, int colb){
  return base + row*stride + (colb ^ ((row & 7) << 4));
}

// ---------------- weight prep: f32 -> bf16 transposed, W_m1@W_m2 collapsed ----------------
__global__ __launch_bounds__(256) void prep_kernel(
    const float* __restrict__ W_in,  const float* __restrict__ W_qkv,
    const float* __restrict__ W_m1,  const float* __restrict__ W_m2,
    const float* __restrict__ b_m1,  const float* __restrict__ b_m2,
    const float* __restrict__ W_gi,  const float* __restrict__ W_gm,
    __bf16* __restrict__ ws, float* __restrict__ bc)
{
  int gt = blockIdx.x*256 + threadIdx.x;
  int NT = gridDim.x*256;
  for (int i = gt; i < 128*128; i += NT){ int n=i>>7, k=i&127; ws[(WS_WIN >>1)+i] = (__bf16)W_in [k*128+n]; }
  for (int i = gt; i < 384*128; i += NT){ int n=i>>7, k=i&127; ws[(WS_WQKV>>1)+i] = (__bf16)W_qkv[k*384+n]; }
  for (int i = gt; i < 256*128; i += NT){ int n=i>>7, k=i&127; ws[(WS_WGI >>1)+i] = (__bf16)W_gi [k*256+n]; }
  for (int i = gt; i < 256*128; i += NT){ int n=i>>7, k=i&127; ws[(WS_WGM >>1)+i] = (__bf16)W_gm [k*256+n]; }
  for (int i = gt; i < 128*128; i += NT){
    int n=i>>7, k=i&127;
    float s = 0.f;
    for (int j=0;j<128;j++) s += W_m1[k*128+j]*W_m2[j*128+n];
    ws[(WS_WC>>1)+i] = (__bf16)s;
  }
  for (int i = gt; i < 128; i += NT){
    float s = b_m2[i];
    for (int j=0;j<128;j++) s += b_m1[j]*W_m2[j*128+i];
    bc[i] = s;
  }
}

// ---------------- fused main kernel ----------------
// LDS plan (53248 B -> 3 blocks/CU), all tiles XOR-swizzled:
//  Q [0,27648)      qkv bf16 36 rows stride 768 ; later: mlp f32 36 rows stride 512 ;
//                   later: gib f32 4 rows stride 1024 @0 + memf f32 32 rows stride 512 @4096
//  A [27648,39936)  amp bf16 48 rows stride 256 (mp; rows 36..47 zero) ; later mem ; later tanh(memory)
//  O [39936,49152)  sout bf16 36 rows stride 256 (attn out -> mem -> mem2)
//  X [49152,53248)  sx bf16 16 rows stride 256 (x; rows 4..15 zero)
__global__ __launch_bounds__(256) void rmc_kernel(
    const float* __restrict__ inputs, const float* __restrict__ memory,
    const float* __restrict__ b_in,   const float* __restrict__ b_qkv,
    const float* __restrict__ lnq_g,  const float* __restrict__ lnq_b,
    const float* __restrict__ ln1_g,  const float* __restrict__ ln1_b,
    const float* __restrict__ ln2_g,  const float* __restrict__ ln2_b,
    const float* __restrict__ b_gi,   const float* __restrict__ b_gm,
    const __bf16* __restrict__ wWin,  const __bf16* __restrict__ wWqkv,
    const __bf16* __restrict__ wWc,   const __bf16* __restrict__ wWgi,
    const __bf16* __restrict__ wWgm,  const float* __restrict__ bc,
    float* __restrict__ out0, float* __restrict__ out1)
{
  __shared__ __align__(16) char smem[53248];
  char* Q = smem;
  char* A = smem + 27648;
  char* O = smem + 39936;
  char* X = smem + 49152;

  const int tid  = threadIdx.x;
  const int lane = tid & 63;
  const int wv   = tid >> 6;
  const int l15  = lane & 15;
  const int lg   = lane >> 4;          // k-group 0..3
  const int b0   = blockIdx.x * BT;

  // ---- P0: stage inputs & memory (vectorized: 8 f32 -> one b128 LDS write) ----
  {
    int r = tid >> 4, c = tid & 15;    // sx: 16 rows x 16 chunks
    bf16x8 h = {};
    if (r < BT){
      const float* gp = inputs + (size_t)(b0+r)*128 + c*8;
      f32x4 a = *(const f32x4*)gp, b = *(const f32x4*)(gp+4);
      h[0]=(__bf16)a[0]; h[1]=(__bf16)a[1]; h[2]=(__bf16)a[2]; h[3]=(__bf16)a[3];
      h[4]=(__bf16)b[0]; h[5]=(__bf16)b[1]; h[6]=(__bf16)b[2]; h[7]=(__bf16)b[3];
    }
    *(bf16x8*)swz(X, r, 256, c*16) = h;
  }
  for (int t = tid; t < 512; t += 256){            // memory: 32 rows x 16 chunks
    int r = t >> 4, c8 = (t & 15)*8;
    const float* gp = memory + (size_t)(b0 + (r>>3))*1024 + (r&7)*128 + c8;
    f32x4 a = *(const f32x4*)gp, b = *(const f32x4*)(gp+4);
    bf16x8 h;
    h[0]=(__bf16)a[0]; h[1]=(__bf16)a[1]; h[2]=(__bf16)a[2]; h[3]=(__bf16)a[3];
    h[4]=(__bf16)b[0]; h[5]=(__bf16)b[1]; h[6]=(__bf16)b[2]; h[7]=(__bf16)b[3];
    *(bf16x8*)swz(A, (r>>3)*S1 + (r&7), 256, c8*2) = h;
  }
  if (tid < 192){                                   // amp pad rows 36..47
    *(bf16x8*)swz(A, RROWS + (tid>>4), 256, (tid&15)*16) = (bf16x8){};
  }
  __syncthreads();

  // ---- P1: x = inputs @ W_in + b_in   (M=16 pad, N=128) ----
  {
    bf16x8 aX[4];
#pragma unroll
    for (int k=0;k<4;k++) aX[k] = *(const bf16x8*)swz(X, l15, 256, k*64 + lg*16);
    f32x4 accX[2];
#pragma unroll
    for (int n=0;n<2;n++){
      int nt = wv*2 + n;
      f32x4 acc = {0.f,0.f,0.f,0.f};
#pragma unroll
      for (int k=0;k<4;k++){
        bf16x8 b = *(const bf16x8*)(wWin + (nt*16 + l15)*128 + k*32 + 8*lg);
        acc = __builtin_amdgcn_mfma_f32_16x16x32_bf16(aX[k], b, acc, 0, 0, 0);
      }
      accX[n] = acc;
    }
    __syncthreads();   // all A-reads of X done before overwrite
#pragma unroll
    for (int n=0;n<2;n++){
#pragma unroll
      for (int r=0;r<4;r++){
        int row = 4*lg + r;
        if (row < BT){
          int col = (wv*2+n)*16 + l15;
          __bf16 h = (__bf16)(accX[n][r] + b_in[col]);
          *(__bf16*)swz(X, row, 256, col*2) = h;            // x (for gi GEMM)
          *(__bf16*)swz(A, row*S1+8, 256, col*2) = h;       // mp slot 8
        }
      }
    }
  }
  __syncthreads();

  // ---- P2: qkv_pre = mp @ W_qkv + b_qkv  (M=48 pad, N=384) ----
  {
    bf16x8 aQ[3][4];
#pragma unroll
    for (int m=0;m<3;m++)
#pragma unroll
      for (int k=0;k<4;k++)
        aQ[m][k] = *(const bf16x8*)swz(A, m*16 + l15, 256, k*64 + lg*16);
    f32x4 accQ[3][6];
#pragma unroll
    for (int m=0;m<3;m++)
#pragma unroll
      for (int n=0;n<6;n++) accQ[m][n] = (f32x4){0.f,0.f,0.f,0.f};
#pragma unroll
    for (int n=0;n<6;n++){
      int nt = wv*6 + n;
#pragma unroll
      for (int k=0;k<4;k++){
        bf16x8 b = *(const bf16x8*)(wWqkv + (nt*16 + l15)*128 + k*32 + 8*lg);
#pragma unroll
        for (int m=0;m<3;m++)
          accQ[m][n] = __builtin_amdgcn_mfma_f32_16x16x32_bf16(aQ[m][k], b, accQ[m][n], 0, 0, 0);
      }
    }
#pragma unroll
    for (int m=0;m<3;m++)
#pragma unroll
      for (int n=0;n<6;n++)
#pragma unroll
        for (int r=0;r<4;r++){
          int row = m*16 + 4*lg + r;
          if (row < RROWS){
            int col = (wv*6+n)*16 + l15;
            *(__bf16*)swz(Q, row, 768, col*2) = (__bf16)(accQ[m][n][r] + b_qkv[col]);
          }
        }
  }
  __syncthreads();

  // ---- P3: LN(qkv) in place + fold q-scale 96^-0.5 ----
  {
    const float QSC = 0.1020620726159658f;
    float gq[6], bq[6];
#pragma unroll
    for (int t=0;t<6;t++){ gq[t] = lnq_g[lane+64*t]; bq[t] = lnq_b[lane+64*t]; }
    for (int r = wv; r < RROWS; r += 4){
      float x[6]; float s = 0.f, sq = 0.f;
#pragma unroll
      for (int t=0;t<6;t++){
        x[t] = (float)*(const __bf16*)swz(Q, r, 768, (lane + 64*t)*2);
        s += x[t]; sq += x[t]*x[t];
      }
#pragma unroll
      for (int o=1;o<64;o<<=1){ s += __shfl_xor(s,o); sq += __shfl_xor(sq,o); }
      float mean = s * (1.f/384.f);
      float var  = sq * (1.f/384.f) - mean*mean;
      float rs   = rsqrtf(var + 1e-5f);
#pragma unroll
      for (int t=0;t<6;t++){
        int c = lane + 64*t;
        float y = gq[t]*(x[t]-mean)*rs + bq[t];
        if ((c % 96) < 32) y *= QSC;
        *(__bf16*)swz(Q, r, 768, c*2) = (__bf16)y;
      }
    }
  }
  __syncthreads();

  // ---- P4: attention (VALU). task = (s,h,q), 144 tasks ----
  if (tid < BT*4*S1){
    int s = tid/36, h = (tid/9)&3, q = tid%9;
    int cb = h*192;               // head byte offset within qkv row
    float qv[32];
#pragma unroll
    for (int t=0;t<4;t++){
      bf16x8 hv = *(const bf16x8*)swz(Q, s*S1+q, 768, cb + t*16);
#pragma unroll
      for (int j=0;j<8;j++) qv[t*8+j] = (float)hv[j];
    }
    float sc[9]; float mx = -1e30f;
#pragma unroll
    for (int kk=0;kk<9;kk++){
      float a = 0.f;
#pragma unroll
      for (int t=0;t<4;t++){
        bf16x8 hv = *(const bf16x8*)swz(Q, s*S1+kk, 768, cb + 64 + t*16);
#pragma unroll
        for (int j=0;j<8;j++) a += qv[t*8+j]*(float)hv[j];
      }
      sc[kk] = a; mx = fmaxf(mx, a);
    }
    float sum = 0.f;
#pragma unroll
    for (int kk=0;kk<9;kk++){ sc[kk] = __expf(sc[kk]-mx); sum += sc[kk]; }
    float inv = 1.f/sum;
    float ov[32];
#pragma unroll
    for (int d=0;d<32;d++) ov[d] = 0.f;
#pragma unroll
    for (int kk=0;kk<9;kk++){
      float p = sc[kk];
#pragma unroll
      for (int t=0;t<4;t++){
        bf16x8 hv = *(const bf16x8*)swz(Q, s*S1+kk, 768, cb + 128 + t*16);
#pragma unroll
        for (int j=0;j<8;j++) ov[t*8+j] += p*(float)hv[j];
      }
    }
#pragma unroll
    for (int t=0;t<4;t++){
      bf16x8 hv;
#pragma unroll
      for (int j=0;j<8;j++) hv[j] = (__bf16)(ov[t*8+j]*inv);
      *(bf16x8*)swz(O, s*S1+q, 256, h*64 + t*16) = hv;
    }
  }
  __syncthreads();

  // ---- P5: mem = LN(mp + out) -> O (bf16) and A (bf16, MLP A-operand) ----
  {
    float g0 = ln1_g[lane], g1 = ln1_g[lane+64], e0 = ln1_b[lane], e1 = ln1_b[lane+64];
    for (int r = wv; r < RROWS; r += 4){
      float t0 = (float)*(const __bf16*)swz(A, r, 256, lane*2)
               + (float)*(const __bf16*)swz(O, r, 256, lane*2);
      float t1 = (float)*(const __bf16*)swz(A, r, 256, (lane+64)*2)
               + (float)*(const __bf16*)swz(O, r, 256, (lane+64)*2);
      float s = t0+t1, sq = t0*t0 + t1*t1;
#pragma unroll
      for (int o=1;o<64;o<<=1){ s += __shfl_xor(s,o); sq += __shfl_xor(sq,o); }
      float mean = s*(1.f/128.f), var = sq*(1.f/128.f) - mean*mean;
      float rs = rsqrtf(var + 1e-5f);
      __bf16 h0 = (__bf16)(g0*(t0-mean)*rs + e0);
      __bf16 h1 = (__bf16)(g1*(t1-mean)*rs + e1);
      *(__bf16*)swz(O, r, 256, lane*2) = h0;      *(__bf16*)swz(A, r, 256, lane*2) = h0;
      *(__bf16*)swz(O, r, 256, (lane+64)*2) = h1; *(__bf16*)swz(A, r, 256, (lane+64)*2) = h1;
    }
  }
  __syncthreads();

  // ---- P6: mlp = mem @ (W_m1 W_m2) + bc -> mlpb (f32, aliases Q) ----
  {
    bf16x8 aM[3][4];
#pragma unroll
    for (int m=0;m<3;m++)
#pragma unroll
      for (int k=0;k<4;k++)
        aM[m][k] = *(const bf16x8*)swz(A, m*16 + l15, 256, k*64 + lg*16);
    f32x4 accM[3][2];
#pragma unroll
    for (int m=0;m<3;m++)
#pragma unroll
      for (int n=0;n<2;n++) accM[m][n] = (f32x4){0.f,0.f,0.f,0.f};
#pragma unroll
    for (int n=0;n<2;n++){
      int nt = wv*2 + n;
#pragma unroll
      for (int k=0;k<4;k++){
        bf16x8 b = *(const bf16x8*)(wWc + (nt*16 + l15)*128 + k*32 + 8*lg);
#pragma unroll
        for (int m=0;m<3;m++)
          accM[m][n] = __builtin_amdgcn_mfma_f32_16x16x32_bf16(aM[m][k], b, accM[m][n], 0, 0, 0);
      }
    }
    // Q region free since P4 (two barriers ago) — safe to write mlpb now
#pragma unroll
    for (int m=0;m<3;m++)
#pragma unroll
      for (int n=0;n<2;n++)
#pragma unroll
        for (int r=0;r<4;r++){
          int row = m*16 + 4*lg + r;
          if (row < RROWS){
            int col = (wv*2+n)*16 + l15;
            *(float*)swz(Q, row, 512, col*4) = accM[m][n][r] + bc[col];
          }
        }
  }
  __syncthreads();

  // ---- P7: mem2 = LN(mlp + mem) -> O (skip slot-8 rows) ----
  {
    float g0 = ln2_g[lane], g1 = ln2_g[lane+64], e0 = ln2_b[lane], e1 = ln2_b[lane+64];
    for (int r = wv; r < RROWS; r += 4){
      if ((r % S1) == 8) continue;
      float t0 = *(const float*)swz(Q, r, 512, lane*4)
               + (float)*(const __bf16*)swz(O, r, 256, lane*2);
      float t1 = *(const float*)swz(Q, r, 512, (lane+64)*4)
               + (float)*(const __bf16*)swz(O, r, 256, (lane+64)*2);
      float s = t0+t1, sq = t0*t0 + t1*t1;
#pragma unroll
      for (int o=1;o<64;o<<=1){ s += __shfl_xor(s,o); sq += __shfl_xor(sq,o); }
      float mean = s*(1.f/128.f), var = sq*(1.f/128.f) - mean*mean;
      float rs = rsqrtf(var + 1e-5f);
      *(__bf16*)swz(O, r, 256, lane*2)      = (__bf16)(g0*(t0-mean)*rs + e0);
      *(__bf16*)swz(O, r, 256, (lane+64)*2) = (__bf16)(g1*(t1-mean)*rs + e1);
    }
  }
  __syncthreads();

  // ---- P8: gi = x @ W_gi + b_gi -> gib (f32, Q rows 0..3 stride 1024);
  //          stage memf (f32, Q+4096) + tanh(memory) (bf16, A rows 0..31) ----
  {
    bf16x8 aG[4];
#pragma unroll
    for (int k=0;k<4;k++) aG[k] = *(const bf16x8*)swz(X, l15, 256, k*64 + lg*16);
    f32x4 accG[4];
#pragma unroll
    for (int n=0;n<4;n++) accG[n] = (f32x4){0.f,0.f,0.f,0.f};
#pragma unroll
    for (int n=0;n<4;n++){
      int nt = wv*4 + n;
#pragma unroll
      for (int k=0;k<4;k++){
        bf16x8 b = *(const bf16x8*)(wWgi + (nt*16 + l15)*128 + k*32 + 8*lg);
        accG[n] = __builtin_amdgcn_mfma_f32_16x16x32_bf16(aG[k], b, accG[n], 0, 0, 0);
      }
    }
#pragma unroll
    for (int n=0;n<4;n++)
#pragma unroll
      for (int r=0;r<4;r++){
        int row = 4*lg + r;
        if (row < BT){
          int col = (wv*4+n)*16 + l15;
          *(float*)swz(Q, row, 1024, col*4) = accG[n][r] + b_gi[col];
        }
      }
    for (int t = tid; t < 512; t += 256){
      int r = t >> 4, c8 = (t & 15)*8;
      const float* gp = memory + (size_t)(b0 + (r>>3))*1024 + (r&7)*128 + c8;
      f32x4 a = *(const f32x4*)gp, b = *(const f32x4*)(gp+4);
      *(f32x4*)swz(Q + 4096, r, 512, c8*4)      = a;
      *(f32x4*)swz(Q + 4096, r, 512, c8*4 + 16) = b;
      bf16x8 h;
      h[0]=(__bf16)tanhf_(a[0]); h[1]=(__bf16)tanhf_(a[1]);
      h[2]=(__bf16)tanhf_(a[2]); h[3]=(__bf16)tanhf_(a[3]);
      h[4]=(__bf16)tanhf_(b[0]); h[5]=(__bf16)tanhf_(b[1]);
      h[6]=(__bf16)tanhf_(b[2]); h[7]=(__bf16)tanhf_(b[3]);
      *(bf16x8*)swz(A, r, 256, c8*2) = h;
    }
  }
  __syncthreads();

  // ---- P9: gm = tanh(memory) @ W_gm + b_gm; fused gates -> global ----
  {
    bf16x8 aT[2][4];
#pragma unroll
    for (int m=0;m<2;m++)
#pragma unroll
      for (int k=0;k<4;k++)
        aT[m][k] = *(const bf16x8*)swz(A, m*16 + l15, 256, k*64 + lg*16);
    f32x4 accT[2][4];
#pragma unroll
    for (int m=0;m<2;m++)
#pragma unroll
      for (int t=0;t<4;t++) accT[m][t] = (f32x4){0.f,0.f,0.f,0.f};
    const int ntl[4] = {2*wv, 2*wv+1, 8+2*wv, 8+2*wv+1};
#pragma unroll
    for (int t=0;t<4;t++){
#pragma unroll
      for (int k=0;k<4;k++){
        bf16x8 b = *(const bf16x8*)(wWgm + (ntl[t]*16 + l15)*128 + k*32 + 8*lg);
#pragma unroll
        for (int m=0;m<2;m++)
          accT[m][t] = __builtin_amdgcn_mfma_f32_16x16x32_bf16(aT[m][k], b, accT[m][t], 0, 0, 0);
      }
    }
#pragma unroll
    for (int m=0;m<2;m++)
#pragma unroll
      for (int p=0;p<2;p++)
#pragma unroll
        for (int r=0;r<4;r++){
          int row = m*16 + 4*lg + r;       // 0..31
          int s = row>>3, j = row&7;
          int c = wv*32 + p*16 + l15;      // 0..127
          float g_i = accT[m][p][r]   + b_gm[c]
                    + *(const float*)swz(Q, s, 1024, c*4);
          float g_f = accT[m][2+p][r] + b_gm[128+c]
                    + *(const float*)swz(Q, s, 1024, (128+c)*4) + 1.0f;
          float ig = sigmoidf_(g_i), fg = sigmoidf_(g_f);
          float m2 = (float)*(const __bf16*)swz(O, s*S1+j, 256, c*2);
          float mo = *(const float*)swz(Q + 4096, row, 512, c*4);
          float nm = ig*tanhf_(m2) + fg*mo;
          size_t o = (size_t)(b0+s)*1024 + (size_t)(j*128 + c);
          out0[o] = nm;
          out1[o] = nm;
        }
  }
}

// ---------------- launch ----------------
extern "C" void kernel_launch(void* const* d_in, const int* in_sizes, int n_in,
                              void* d_out, int out_size, void* d_ws, size_t ws_size,
                              hipStream_t stream) {
  const float* inputs = (const float*)d_in[0];
  const float* memory = (const float*)d_in[1];
  const float* W_in   = (const float*)d_in[2];
  const float* b_in   = (const float*)d_in[3];
  const float* W_qkv  = (const float*)d_in[4];
  const float* b_qkv  = (const float*)d_in[5];
  const float* lnq_g  = (const float*)d_in[6];
  const float* lnq_b  = (const float*)d_in[7];
  const float* ln1_g  = (const float*)d_in[8];
  const float* ln1_b  = (const float*)d_in[9];
  const float* W_m1   = (const float*)d_in[10];
  const float* b_m1   = (const float*)d_in[11];
  const float* W_m2   = (const float*)d_in[12];
  const float* b_m2   = (const float*)d_in[13];
  const float* ln2_g  = (const float*)d_in[14];
  const float* ln2_b  = (const float*)d_in[15];
  const float* W_gi   = (const float*)d_in[16];
  const float* b_gi   = (const float*)d_in[17];
  const float* W_gm   = (const float*)d_in[18];
  const float* b_gm   = (const float*)d_in[19];

  __bf16* ws16 = (__bf16*)d_ws;
  float* bc = (float*)((char*)d_ws + WS_BC);
  const __bf16* wWin  = (const __bf16*)((char*)d_ws + WS_WIN);
  const __bf16* wWqkv = (const __bf16*)((char*)d_ws + WS_WQKV);
  const __bf16* wWc   = (const __bf16*)((char*)d_ws + WS_WC);
  const __bf16* wWgi  = (const __bf16*)((char*)d_ws + WS_WGI);
  const __bf16* wWgm  = (const __bf16*)((char*)d_ws + WS_WGM);

  float* out0 = (float*)d_out;
  float* out1 = out0 + (size_t)BATCH*1024;

  prep_kernel<<<dim3(256), dim3(256), 0, stream>>>(
      W_in, W_qkv, W_m1, W_m2, b_m1, b_m2, W_gi, W_gm, ws16, bc);

  rmc_kernel<<<dim3(NBLK), dim3(256), 0, stream>>>(
      inputs, memory, b_in, b_qkv, lnq_g, lnq_b, ln1_g, ln1_b, ln2_g, ln2_b,
      b_gi, b_gm, wWin, wWqkv, wWc, wWgi, wWgm, bc, out0, out1);
}